// Round 2
// baseline (241.737 us; speedup 1.0000x reference)
//
#include <hip/hip_runtime.h>

// YOLO loss: BATCH=16384, SNUM=7 -> CELLS=49, BNUM=2, CLSS=20 -> ELE=30.
// Memory-bound streaming reduction: 193 MB in, 4 B out.
//
// v3: coalesced LDS transpose (like v0) but PHASED through a single 30 KB
// buffer: stage P -> read cp[30] to VGPRs -> stage T (same buffer) -> read
// ct[30]. LDS per block = 30.7 KB -> 5 blocks/CU = 20 waves/CU (v0's 64 KB
// allowed only 2 blocks/CU), while keeping fully-coalesced float4 staging
// (v2's per-thread stride-120B gather was TA-bound at 2.8 B/cy/CU).
// Staging is load-all-8/store-all-8 with a static-indexed r[8] so 8 float4
// loads per thread are in flight. LDS layout is UNPADDED (linear writes,
// ds_write_b128 conflict-free); compute reads are float2 at stride 30
// floats -> 4-way bank conflict (~1.58x), ~6 us total LDS pipe time -- not
// on the critical path.

#define ELE 30
#define TPB 256
#define CPB 256
#define NV4 (CPB * ELE / 4)            // 1920 float4 per input per block
#define TOTAL_CELLS (16384 * 49)       // 802816; /256 = 3136 blocks exactly

__global__ __launch_bounds__(TPB, 5) void yolo_loss_kernel(
    const float* __restrict__ P, const float* __restrict__ T,
    float* __restrict__ out)
{
    __shared__ float sbuf[CPB * ELE];      // 30720 B, reused for P then T
    __shared__ float swave[TPB / 64];

    const int tid = threadIdx.x;
    const size_t base = (size_t)blockIdx.x * (CPB * ELE);   // *4B = 30720 -> 16B aligned

    const float4* __restrict__ P4 = reinterpret_cast<const float4*>(P + base);
    const float4* __restrict__ T4 = reinterpret_cast<const float4*>(T + base);
    float4* s4 = reinterpret_cast<float4*>(sbuf);

    // ---- phase 1: stage P (coalesced), transpose-read into registers ----
    float4 r[8];
    #pragma unroll
    for (int i = 0; i < 8; ++i) { int v = i * TPB + tid; if (v < NV4) r[i] = P4[v]; }
    #pragma unroll
    for (int i = 0; i < 8; ++i) { int v = i * TPB + tid; if (v < NV4) s4[v] = r[i]; }
    __syncthreads();

    float cp[ELE];
    const float2* c2 = reinterpret_cast<const float2*>(sbuf) + tid * (ELE / 2);
    #pragma unroll
    for (int k = 0; k < ELE / 2; ++k) {
        float2 v = c2[k];
        cp[2 * k]     = v.x;
        cp[2 * k + 1] = v.y;
    }
    __syncthreads();   // everyone done reading P before T overwrites sbuf

    // ---- phase 2: stage T (same buffer), transpose-read ----
    #pragma unroll
    for (int i = 0; i < 8; ++i) { int v = i * TPB + tid; if (v < NV4) r[i] = T4[v]; }
    #pragma unroll
    for (int i = 0; i < 8; ++i) { int v = i * TPB + tid; if (v < NV4) s4[v] = r[i]; }
    __syncthreads();

    float ct[ELE];
    #pragma unroll
    for (int k = 0; k < ELE / 2; ++k) {
        float2 v = c2[k];
        ct[2 * k]     = v.x;
        ct[2 * k + 1] = v.y;
    }

    // ---- per-cell loss ----
    const float conf_flag = ct[5];
    const float coord = (conf_flag > 0.0f) ? 1.0f : 0.0f;
    const float noobj = (conf_flag == 0.0f) ? 1.0f : 0.0f;

    // confidence diffs (fields 4 and 9)
    const float dc0 = cp[4] - ct[4];
    const float dc1 = cp[9] - ct[9];
    const float noobj_conf = noobj * (dc0 * dc0 + dc1 * dc1);

    // corners + areas (areas from corners, matching reference rounding)
    float px1[2], py1[2], px2[2], py2[2], pa[2];
    float tx1[2], ty1[2], tx2[2], ty2[2], ta[2];
    #pragma unroll
    for (int b = 0; b < 2; ++b) {
        const int o = b * 5;
        float cx = cp[o + 0], cy = cp[o + 1], w = cp[o + 2], h = cp[o + 3];
        px1[b] = cx - w * 0.5f; py1[b] = cy - h * 0.5f;
        px2[b] = cx + w * 0.5f; py2[b] = cy + h * 0.5f;
        pa[b]  = (px2[b] - px1[b]) * (py2[b] - py1[b]);
        cx = ct[o + 0]; cy = ct[o + 1]; w = ct[o + 2]; h = ct[o + 3];
        tx1[b] = cx - w * 0.5f; ty1[b] = cy - h * 0.5f;
        tx2[b] = cx + w * 0.5f; ty2[b] = cy + h * 0.5f;
        ta[b]  = (tx2[b] - tx1[b]) * (ty2[b] - ty1[b]);
    }

    // pairwise IoU: iou[p][t]
    float iou[2][2];
    #pragma unroll
    for (int p = 0; p < 2; ++p) {
        #pragma unroll
        for (int t = 0; t < 2; ++t) {
            float lx = fmaxf(px1[p], tx1[t]);
            float ly = fmaxf(py1[p], ty1[t]);
            float rx = fminf(px2[p], tx2[t]);
            float ry = fminf(py2[p], ty2[t]);
            float iw = fmaxf(rx - lx, 0.0f);
            float ih = fmaxf(ry - ly, 0.0f);
            float inter = iw * ih;
            iou[p][t] = inter / (pa[p] + ta[t] - inter + 1e-10f);
        }
    }

    // argmax over p per target t; first-max tiebreak -> strict '>' for idx 1
    const int b0 = (iou[1][0] > iou[0][0]) ? 1 : 0;
    const int b1 = (iou[1][1] > iou[0][1]) ? 1 : 0;
    const float resp0 = coord * ((b0 == 0 || b1 == 0) ? 1.0f : 0.0f);
    const float resp1 = coord * ((b0 == 1 || b1 == 1) ? 1.0f : 0.0f);

    const float obj_conf = resp0 * dc0 * dc0 + resp1 * dc1 * dc1;

    float d;
    float center = 0.0f, wh = 0.0f;
    d = cp[0] - ct[0]; center += resp0 * d * d;
    d = cp[1] - ct[1]; center += resp0 * d * d;
    d = cp[5] - ct[5]; center += resp1 * d * d;
    d = cp[6] - ct[6]; center += resp1 * d * d;
    d = cp[2] - ct[2]; wh += resp0 * d * d;
    d = cp[3] - ct[3]; wh += resp0 * d * d;
    d = cp[7] - ct[7]; wh += resp1 * d * d;
    d = cp[8] - ct[8]; wh += resp1 * d * d;

    float cls = 0.0f;
    #pragma unroll
    for (int k = 10; k < 30; ++k) {
        d = cp[k] - ct[k];
        cls += d * d;
    }
    cls *= coord;

    float total = 5.0f * (center + wh) + obj_conf + 0.5f * noobj_conf + cls;

    // ---- reduction: wave shuffle -> LDS -> one atomic per block ----
    #pragma unroll
    for (int off = 32; off > 0; off >>= 1)
        total += __shfl_down(total, off, 64);

    const int wid = tid >> 6;
    const int lane = tid & 63;
    if (lane == 0) swave[wid] = total;
    __syncthreads();
    if (tid == 0) {
        float s = swave[0] + swave[1] + swave[2] + swave[3];
        atomicAdd(out, s);
    }
}

extern "C" void kernel_launch(void* const* d_in, const int* in_sizes, int n_in,
                              void* d_out, int out_size, void* d_ws, size_t ws_size,
                              hipStream_t stream) {
    const float* P = (const float*)d_in[0];
    const float* T = (const float*)d_in[1];
    float* out = (float*)d_out;

    hipMemsetAsync(out, 0, sizeof(float), stream);   // d_out is poisoned 0xAA
    yolo_loss_kernel<<<dim3(TOTAL_CELLS / CPB), dim3(TPB), 0, stream>>>(P, T, out);
}

// Round 3
// 220.374 us; speedup vs baseline: 1.0969x; 1.0969x over previous
//
#include <hip/hip_runtime.h>

// YOLO loss: BATCH=16384, SNUM=7 -> CELLS=49, BNUM=2, CLSS=20 -> ELE=30.
// Memory-bound streaming reduction: 193 MB in, 4 B out.
//
// v4: v3's phased single-buffer LDS transpose (stage P -> read cp ->
// stage T -> read ct; 30.7 KB LDS -> 4-5 blocks/CU) with the two register-
// pressure bombs removed:
//   - no hand-batched r[8] (was 32 VGPRs live across the whole staging
//     loop): plain load->store; the compiler batches loads within its
//     budget and 16-20 resident waves/CU provide the in-flight bytes
//     (need ~9 KB/CU = 10 B/cyc x 900 cyc; each wave-load = 1 KB).
//   - __launch_bounds__(256,4): VGPR cap 128 >> ~75 live worst case.
// v3 spilled to scratch (VGPR=44, 188 MB WRITE_SIZE, hbm_bytes 2x input)
// and ran 109 us; v4 must show WRITE_SIZE ~0 to confirm the diagnosis.

#define ELE 30
#define TPB 256
#define CPB 256
#define NV4 (CPB * ELE / 4)            // 1920 float4 per input per block
#define TOTAL_CELLS (16384 * 49)       // 802816; /256 = 3136 blocks exactly

__global__ __launch_bounds__(TPB, 4) void yolo_loss_kernel(
    const float* __restrict__ P, const float* __restrict__ T,
    float* __restrict__ out)
{
    __shared__ float sbuf[CPB * ELE];      // 30720 B, reused for P then T
    __shared__ float swave[TPB / 64];

    const int tid = threadIdx.x;
    const size_t base = (size_t)blockIdx.x * (CPB * ELE);   // *4B = 30720 -> 16B aligned

    const float4* __restrict__ P4 = reinterpret_cast<const float4*>(P + base);
    const float4* __restrict__ T4 = reinterpret_cast<const float4*>(T + base);
    float4* s4 = reinterpret_cast<float4*>(sbuf);

    // ---- phase 1: stage P (coalesced float4, linear LDS), transpose-read ----
    #pragma unroll
    for (int i = 0; i < 8; ++i) {
        int v = i * TPB + tid;
        if (v < NV4) s4[v] = P4[v];        // tail: i=7 active for tid<128 (whole waves)
    }
    __syncthreads();

    float cp[ELE];
    const float2* c2 = reinterpret_cast<const float2*>(sbuf) + tid * (ELE / 2);
    #pragma unroll
    for (int k = 0; k < ELE / 2; ++k) {
        float2 v = c2[k];
        cp[2 * k]     = v.x;
        cp[2 * k + 1] = v.y;
    }
    __syncthreads();   // everyone done reading P before T overwrites sbuf

    // ---- phase 2: stage T (same buffer), transpose-read ----
    #pragma unroll
    for (int i = 0; i < 8; ++i) {
        int v = i * TPB + tid;
        if (v < NV4) s4[v] = T4[v];
    }
    __syncthreads();

    float ct[ELE];
    #pragma unroll
    for (int k = 0; k < ELE / 2; ++k) {
        float2 v = c2[k];
        ct[2 * k]     = v.x;
        ct[2 * k + 1] = v.y;
    }

    // ---- per-cell loss ----
    const float conf_flag = ct[5];
    const float coord = (conf_flag > 0.0f) ? 1.0f : 0.0f;
    const float noobj = (conf_flag == 0.0f) ? 1.0f : 0.0f;

    // confidence diffs (fields 4 and 9)
    const float dc0 = cp[4] - ct[4];
    const float dc1 = cp[9] - ct[9];
    const float noobj_conf = noobj * (dc0 * dc0 + dc1 * dc1);

    // corners + areas (areas from corners, matching reference rounding)
    float px1[2], py1[2], px2[2], py2[2], pa[2];
    float tx1[2], ty1[2], tx2[2], ty2[2], ta[2];
    #pragma unroll
    for (int b = 0; b < 2; ++b) {
        const int o = b * 5;
        float cx = cp[o + 0], cy = cp[o + 1], w = cp[o + 2], h = cp[o + 3];
        px1[b] = cx - w * 0.5f; py1[b] = cy - h * 0.5f;
        px2[b] = cx + w * 0.5f; py2[b] = cy + h * 0.5f;
        pa[b]  = (px2[b] - px1[b]) * (py2[b] - py1[b]);
        cx = ct[o + 0]; cy = ct[o + 1]; w = ct[o + 2]; h = ct[o + 3];
        tx1[b] = cx - w * 0.5f; ty1[b] = cy - h * 0.5f;
        tx2[b] = cx + w * 0.5f; ty2[b] = cy + h * 0.5f;
        ta[b]  = (tx2[b] - tx1[b]) * (ty2[b] - ty1[b]);
    }

    // pairwise IoU: iou[p][t]
    float iou[2][2];
    #pragma unroll
    for (int p = 0; p < 2; ++p) {
        #pragma unroll
        for (int t = 0; t < 2; ++t) {
            float lx = fmaxf(px1[p], tx1[t]);
            float ly = fmaxf(py1[p], ty1[t]);
            float rx = fminf(px2[p], tx2[t]);
            float ry = fminf(py2[p], ty2[t]);
            float iw = fmaxf(rx - lx, 0.0f);
            float ih = fmaxf(ry - ly, 0.0f);
            float inter = iw * ih;
            iou[p][t] = inter / (pa[p] + ta[t] - inter + 1e-10f);
        }
    }

    // argmax over p per target t; first-max tiebreak -> strict '>' for idx 1
    const int b0 = (iou[1][0] > iou[0][0]) ? 1 : 0;
    const int b1 = (iou[1][1] > iou[0][1]) ? 1 : 0;
    const float resp0 = coord * ((b0 == 0 || b1 == 0) ? 1.0f : 0.0f);
    const float resp1 = coord * ((b0 == 1 || b1 == 1) ? 1.0f : 0.0f);

    const float obj_conf = resp0 * dc0 * dc0 + resp1 * dc1 * dc1;

    float d;
    float center = 0.0f, wh = 0.0f;
    d = cp[0] - ct[0]; center += resp0 * d * d;
    d = cp[1] - ct[1]; center += resp0 * d * d;
    d = cp[5] - ct[5]; center += resp1 * d * d;
    d = cp[6] - ct[6]; center += resp1 * d * d;
    d = cp[2] - ct[2]; wh += resp0 * d * d;
    d = cp[3] - ct[3]; wh += resp0 * d * d;
    d = cp[7] - ct[7]; wh += resp1 * d * d;
    d = cp[8] - ct[8]; wh += resp1 * d * d;

    float cls = 0.0f;
    #pragma unroll
    for (int k = 10; k < 30; ++k) {
        d = cp[k] - ct[k];
        cls += d * d;
    }
    cls *= coord;

    float total = 5.0f * (center + wh) + obj_conf + 0.5f * noobj_conf + cls;

    // ---- reduction: wave shuffle -> LDS -> one atomic per block ----
    #pragma unroll
    for (int off = 32; off > 0; off >>= 1)
        total += __shfl_down(total, off, 64);

    const int wid = tid >> 6;
    const int lane = tid & 63;
    if (lane == 0) swave[wid] = total;
    __syncthreads();
    if (tid == 0) {
        float s = swave[0] + swave[1] + swave[2] + swave[3];
        atomicAdd(out, s);
    }
}

extern "C" void kernel_launch(void* const* d_in, const int* in_sizes, int n_in,
                              void* d_out, int out_size, void* d_ws, size_t ws_size,
                              hipStream_t stream) {
    const float* P = (const float*)d_in[0];
    const float* T = (const float*)d_in[1];
    float* out = (float*)d_out;

    hipMemsetAsync(out, 0, sizeof(float), stream);   // d_out is poisoned 0xAA
    yolo_loss_kernel<<<dim3(TOTAL_CELLS / CPB), dim3(TPB), 0, stream>>>(P, T, out);
}

// Round 4
// 209.310 us; speedup vs baseline: 1.1549x; 1.0529x over previous
//
#include <hip/hip_runtime.h>

// YOLO loss: BATCH=16384, SNUM=7 -> CELLS=49, BNUM=2, CLSS=20 -> ELE=30.
// Memory-bound streaming reduction: 193 MB in, 4 B out.
//
// v5: kill the same-address atomic. v0/v2/v4 (occupancy 17%/62%/41%,
// totally different data paths) all landed 78-88 us with delivered BW
// pinned at ~2.3 TB/s -- structure-invariant floor => common serializer.
// The only shared component: 3136 device-scope atomicAdds to ONE address
// (cross-XCD coherence point, ~25 ns each ~= 78 us). Replace with
// per-block partial stores to d_ws (distinct addresses, no contention)
// + a tiny single-block reduce kernel that writes out directly (also
// removes the memset dispatch). Data path identical to v4 for clean A/B.

#define ELE 30
#define TPB 256
#define CPB 256
#define NV4 (CPB * ELE / 4)            // 1920 float4 per input per block
#define TOTAL_CELLS (16384 * 49)       // 802816; /256 = 3136 blocks exactly
#define NBLK (TOTAL_CELLS / CPB)       // 3136 partials

__global__ __launch_bounds__(TPB, 4) void yolo_loss_kernel(
    const float* __restrict__ P, const float* __restrict__ T,
    float* __restrict__ partial)
{
    __shared__ float sbuf[CPB * ELE];      // 30720 B, reused for P then T
    __shared__ float swave[TPB / 64];

    const int tid = threadIdx.x;
    const size_t base = (size_t)blockIdx.x * (CPB * ELE);   // *4B = 30720 -> 16B aligned

    const float4* __restrict__ P4 = reinterpret_cast<const float4*>(P + base);
    const float4* __restrict__ T4 = reinterpret_cast<const float4*>(T + base);
    float4* s4 = reinterpret_cast<float4*>(sbuf);

    // ---- phase 1: stage P (coalesced float4, linear LDS), transpose-read ----
    #pragma unroll
    for (int i = 0; i < 8; ++i) {
        int v = i * TPB + tid;
        if (v < NV4) s4[v] = P4[v];        // tail: i=7 active for tid<128 (whole waves)
    }
    __syncthreads();

    float cp[ELE];
    const float2* c2 = reinterpret_cast<const float2*>(sbuf) + tid * (ELE / 2);
    #pragma unroll
    for (int k = 0; k < ELE / 2; ++k) {
        float2 v = c2[k];
        cp[2 * k]     = v.x;
        cp[2 * k + 1] = v.y;
    }
    __syncthreads();   // everyone done reading P before T overwrites sbuf

    // ---- phase 2: stage T (same buffer), transpose-read ----
    #pragma unroll
    for (int i = 0; i < 8; ++i) {
        int v = i * TPB + tid;
        if (v < NV4) s4[v] = T4[v];
    }
    __syncthreads();

    float ct[ELE];
    #pragma unroll
    for (int k = 0; k < ELE / 2; ++k) {
        float2 v = c2[k];
        ct[2 * k]     = v.x;
        ct[2 * k + 1] = v.y;
    }

    // ---- per-cell loss ----
    const float conf_flag = ct[5];
    const float coord = (conf_flag > 0.0f) ? 1.0f : 0.0f;
    const float noobj = (conf_flag == 0.0f) ? 1.0f : 0.0f;

    // confidence diffs (fields 4 and 9)
    const float dc0 = cp[4] - ct[4];
    const float dc1 = cp[9] - ct[9];
    const float noobj_conf = noobj * (dc0 * dc0 + dc1 * dc1);

    // corners + areas (areas from corners, matching reference rounding)
    float px1[2], py1[2], px2[2], py2[2], pa[2];
    float tx1[2], ty1[2], tx2[2], ty2[2], ta[2];
    #pragma unroll
    for (int b = 0; b < 2; ++b) {
        const int o = b * 5;
        float cx = cp[o + 0], cy = cp[o + 1], w = cp[o + 2], h = cp[o + 3];
        px1[b] = cx - w * 0.5f; py1[b] = cy - h * 0.5f;
        px2[b] = cx + w * 0.5f; py2[b] = cy + h * 0.5f;
        pa[b]  = (px2[b] - px1[b]) * (py2[b] - py1[b]);
        cx = ct[o + 0]; cy = ct[o + 1]; w = ct[o + 2]; h = ct[o + 3];
        tx1[b] = cx - w * 0.5f; ty1[b] = cy - h * 0.5f;
        tx2[b] = cx + w * 0.5f; ty2[b] = cy + h * 0.5f;
        ta[b]  = (tx2[b] - tx1[b]) * (ty2[b] - ty1[b]);
    }

    // pairwise IoU: iou[p][t]
    float iou[2][2];
    #pragma unroll
    for (int p = 0; p < 2; ++p) {
        #pragma unroll
        for (int t = 0; t < 2; ++t) {
            float lx = fmaxf(px1[p], tx1[t]);
            float ly = fmaxf(py1[p], ty1[t]);
            float rx = fminf(px2[p], tx2[t]);
            float ry = fminf(py2[p], ty2[t]);
            float iw = fmaxf(rx - lx, 0.0f);
            float ih = fmaxf(ry - ly, 0.0f);
            float inter = iw * ih;
            iou[p][t] = inter / (pa[p] + ta[t] - inter + 1e-10f);
        }
    }

    // argmax over p per target t; first-max tiebreak -> strict '>' for idx 1
    const int b0 = (iou[1][0] > iou[0][0]) ? 1 : 0;
    const int b1 = (iou[1][1] > iou[0][1]) ? 1 : 0;
    const float resp0 = coord * ((b0 == 0 || b1 == 0) ? 1.0f : 0.0f);
    const float resp1 = coord * ((b0 == 1 || b1 == 1) ? 1.0f : 0.0f);

    const float obj_conf = resp0 * dc0 * dc0 + resp1 * dc1 * dc1;

    float d;
    float center = 0.0f, wh = 0.0f;
    d = cp[0] - ct[0]; center += resp0 * d * d;
    d = cp[1] - ct[1]; center += resp0 * d * d;
    d = cp[5] - ct[5]; center += resp1 * d * d;
    d = cp[6] - ct[6]; center += resp1 * d * d;
    d = cp[2] - ct[2]; wh += resp0 * d * d;
    d = cp[3] - ct[3]; wh += resp0 * d * d;
    d = cp[7] - ct[7]; wh += resp1 * d * d;
    d = cp[8] - ct[8]; wh += resp1 * d * d;

    float cls = 0.0f;
    #pragma unroll
    for (int k = 10; k < 30; ++k) {
        d = cp[k] - ct[k];
        cls += d * d;
    }
    cls *= coord;

    float total = 5.0f * (center + wh) + obj_conf + 0.5f * noobj_conf + cls;

    // ---- reduction: wave shuffle -> LDS -> one partial store per block ----
    #pragma unroll
    for (int off = 32; off > 0; off >>= 1)
        total += __shfl_down(total, off, 64);

    const int wid = tid >> 6;
    const int lane = tid & 63;
    if (lane == 0) swave[wid] = total;
    __syncthreads();
    if (tid == 0) {
        partial[blockIdx.x] = swave[0] + swave[1] + swave[2] + swave[3];
    }
}

__global__ __launch_bounds__(1024) void reduce_kernel(
    const float* __restrict__ partial, float* __restrict__ out)
{
    __shared__ float sw[16];
    const int tid = threadIdx.x;

    float s = 0.0f;
    for (int i = tid; i < NBLK; i += 1024)
        s += partial[i];

    #pragma unroll
    for (int off = 32; off > 0; off >>= 1)
        s += __shfl_down(s, off, 64);

    const int wid = tid >> 6;
    const int lane = tid & 63;
    if (lane == 0) sw[wid] = s;
    __syncthreads();
    if (tid == 0) {
        float t = 0.0f;
        #pragma unroll
        for (int i = 0; i < 16; ++i) t += sw[i];
        *out = t;           // unconditional write: no memset needed
    }
}

extern "C" void kernel_launch(void* const* d_in, const int* in_sizes, int n_in,
                              void* d_out, int out_size, void* d_ws, size_t ws_size,
                              hipStream_t stream) {
    const float* P = (const float*)d_in[0];
    const float* T = (const float*)d_in[1];
    float* out = (float*)d_out;
    float* partial = (float*)d_ws;        // needs NBLK*4 = 12.5 KB of workspace

    yolo_loss_kernel<<<dim3(NBLK), dim3(TPB), 0, stream>>>(P, T, partial);
    reduce_kernel<<<dim3(1), dim3(1024), 0, stream>>>(partial, out);
}

// Round 5
// 205.003 us; speedup vs baseline: 1.1792x; 1.0210x over previous
//
#include <hip/hip_runtime.h>

// YOLO loss: BATCH=16384, SNUM=7 -> CELLS=49, BNUM=2, CLSS=20 -> ELE=30.
// Memory-bound streaming reduction: 193 MB in, 4 B out.
//
// v6: Little's-law fix. All previous versions (v0/v2/v4/v5) pinned at
// ~2.5 TB/s delivered regardless of structure/occupancy because VGPR-staged
// loads cap in-flight bytes at ~1.3 MB chip-wide (need ~2.4-3.8 MB for
// 6.3 TB/s at ~400-600 ns loaded latency). Fix: __builtin_amdgcn_global_load_lds
// width=16 -- async global->LDS, ZERO VGPRs per outstanding load.
//   - 1 wave (64 threads) per block, 64 cells; P|T staged into one linear
//     15,360 B LDS region as 15 back-to-back full-wave async loads
//     (iteration 7 straddles P/T with a per-lane pointer select; per-lane
//     GLOBAL addresses are legal, LDS dest stays linear = wave-uniform
//     base + lane*16, per m104).
//   - one __syncthreads (drains vmcnt), transpose-read, compute,
//     wave-reduce, per-block partial store (no atomic, per v5).
//   - LDS unpadded (padding breaks global_load_lds); stride-30 float2
//     reads = 4-way bank conflict, ~1.6x on ~10 us LDS-pipe time, off
//     the critical path.
// 15 KB in flight per wave x 10 blocks/CU = ~150 KB/CU >> ~10 KB needed.

#define ELE 30
#define TPB 64
#define CPB 64
#define FLT_PER_IN (CPB * ELE)          // 1920 floats per input per block
#define NV4 (FLT_PER_IN / 4)            // 480 float4 per input per block
#define TOTAL_CELLS (16384 * 49)        // 802816
#define NBLK (TOTAL_CELLS / CPB)        // 12544 blocks/partials

typedef __attribute__((address_space(3))) float       lds_f;
typedef const __attribute__((address_space(1))) float glb_f;

__device__ __forceinline__ void gl_lds16(const float* g, float* l) {
    // 16-byte-per-lane async global->LDS (gfx950: global_load_lds_dwordx4)
    __builtin_amdgcn_global_load_lds((glb_f*)g, (lds_f*)l, 16, 0, 0);
}

__global__ __launch_bounds__(TPB) void yolo_loss_kernel(
    const float* __restrict__ P, const float* __restrict__ T,
    float* __restrict__ partial)
{
    __shared__ float sbuf[FLT_PER_IN * 2];   // 15360 B: P at [0,1920), T at [1920,3840)

    const int tid = threadIdx.x;
    const size_t base = (size_t)blockIdx.x * FLT_PER_IN;   // *4B = 7680 -> 16B aligned
    const float* __restrict__ Pb = P + base;
    const float* __restrict__ Tb = T + base;

    // ---- stage P|T: 15 full-wave async loads, all in flight at once ----
    #pragma unroll
    for (int j = 0; j < 15; ++j) {
        const int v = j * 64 + tid;                 // float4 index in [0, 960)
        const int vv = (v < NV4) ? v : (v - NV4);
        const float* src = (v < NV4) ? Pb : Tb;     // per-lane global addr: legal
        gl_lds16(src + (size_t)vv * 4, sbuf + (size_t)v * 4);  // LDS linear: lane0 = wave base
    }
    __syncthreads();    // compiler emits s_waitcnt vmcnt(0) before s_barrier

    // ---- transpose-read this thread's cell ----
    float cp[ELE], ct[ELE];
    {
        const float2* c2p = reinterpret_cast<const float2*>(sbuf + tid * ELE);
        const float2* c2t = reinterpret_cast<const float2*>(sbuf + FLT_PER_IN + tid * ELE);
        #pragma unroll
        for (int k = 0; k < ELE / 2; ++k) {
            float2 a = c2p[k];
            cp[2 * k] = a.x; cp[2 * k + 1] = a.y;
            float2 b = c2t[k];
            ct[2 * k] = b.x; ct[2 * k + 1] = b.y;
        }
    }

    // ---- per-cell loss ----
    const float conf_flag = ct[5];
    const float coord = (conf_flag > 0.0f) ? 1.0f : 0.0f;
    const float noobj = (conf_flag == 0.0f) ? 1.0f : 0.0f;

    // confidence diffs (fields 4 and 9)
    const float dc0 = cp[4] - ct[4];
    const float dc1 = cp[9] - ct[9];
    const float noobj_conf = noobj * (dc0 * dc0 + dc1 * dc1);

    // corners + areas (areas from corners, matching reference rounding)
    float px1[2], py1[2], px2[2], py2[2], pa[2];
    float tx1[2], ty1[2], tx2[2], ty2[2], ta[2];
    #pragma unroll
    for (int b = 0; b < 2; ++b) {
        const int o = b * 5;
        float cx = cp[o + 0], cy = cp[o + 1], w = cp[o + 2], h = cp[o + 3];
        px1[b] = cx - w * 0.5f; py1[b] = cy - h * 0.5f;
        px2[b] = cx + w * 0.5f; py2[b] = cy + h * 0.5f;
        pa[b]  = (px2[b] - px1[b]) * (py2[b] - py1[b]);
        cx = ct[o + 0]; cy = ct[o + 1]; w = ct[o + 2]; h = ct[o + 3];
        tx1[b] = cx - w * 0.5f; ty1[b] = cy - h * 0.5f;
        tx2[b] = cx + w * 0.5f; ty2[b] = cy + h * 0.5f;
        ta[b]  = (tx2[b] - tx1[b]) * (ty2[b] - ty1[b]);
    }

    // pairwise IoU: iou[p][t]
    float iou[2][2];
    #pragma unroll
    for (int p = 0; p < 2; ++p) {
        #pragma unroll
        for (int t = 0; t < 2; ++t) {
            float lx = fmaxf(px1[p], tx1[t]);
            float ly = fmaxf(py1[p], ty1[t]);
            float rx = fminf(px2[p], tx2[t]);
            float ry = fminf(py2[p], ty2[t]);
            float iw = fmaxf(rx - lx, 0.0f);
            float ih = fmaxf(ry - ly, 0.0f);
            float inter = iw * ih;
            iou[p][t] = inter / (pa[p] + ta[t] - inter + 1e-10f);
        }
    }

    // argmax over p per target t; first-max tiebreak -> strict '>' for idx 1
    const int b0 = (iou[1][0] > iou[0][0]) ? 1 : 0;
    const int b1 = (iou[1][1] > iou[0][1]) ? 1 : 0;
    const float resp0 = coord * ((b0 == 0 || b1 == 0) ? 1.0f : 0.0f);
    const float resp1 = coord * ((b0 == 1 || b1 == 1) ? 1.0f : 0.0f);

    const float obj_conf = resp0 * dc0 * dc0 + resp1 * dc1 * dc1;

    float d;
    float center = 0.0f, wh = 0.0f;
    d = cp[0] - ct[0]; center += resp0 * d * d;
    d = cp[1] - ct[1]; center += resp0 * d * d;
    d = cp[5] - ct[5]; center += resp1 * d * d;
    d = cp[6] - ct[6]; center += resp1 * d * d;
    d = cp[2] - ct[2]; wh += resp0 * d * d;
    d = cp[3] - ct[3]; wh += resp0 * d * d;
    d = cp[7] - ct[7]; wh += resp1 * d * d;
    d = cp[8] - ct[8]; wh += resp1 * d * d;

    float cls = 0.0f;
    #pragma unroll
    for (int k = 10; k < 30; ++k) {
        d = cp[k] - ct[k];
        cls += d * d;
    }
    cls *= coord;

    float total = 5.0f * (center + wh) + obj_conf + 0.5f * noobj_conf + cls;

    // ---- wave reduction -> one partial store per block (no atomic) ----
    #pragma unroll
    for (int off = 32; off > 0; off >>= 1)
        total += __shfl_down(total, off, 64);

    if (tid == 0)
        partial[blockIdx.x] = total;
}

__global__ __launch_bounds__(1024) void reduce_kernel(
    const float* __restrict__ partial, float* __restrict__ out)
{
    __shared__ float sw[16];
    const int tid = threadIdx.x;

    float s = 0.0f;
    for (int i = tid; i < NBLK; i += 1024)
        s += partial[i];

    #pragma unroll
    for (int off = 32; off > 0; off >>= 1)
        s += __shfl_down(s, off, 64);

    const int wid = tid >> 6;
    const int lane = tid & 63;
    if (lane == 0) sw[wid] = s;
    __syncthreads();
    if (tid == 0) {
        float t = 0.0f;
        #pragma unroll
        for (int i = 0; i < 16; ++i) t += sw[i];
        *out = t;           // unconditional write: no memset needed
    }
}

extern "C" void kernel_launch(void* const* d_in, const int* in_sizes, int n_in,
                              void* d_out, int out_size, void* d_ws, size_t ws_size,
                              hipStream_t stream) {
    const float* P = (const float*)d_in[0];
    const float* T = (const float*)d_in[1];
    float* out = (float*)d_out;
    float* partial = (float*)d_ws;        // needs NBLK*4 = 50,176 B of workspace

    yolo_loss_kernel<<<dim3(NBLK), dim3(TPB), 0, stream>>>(P, T, partial);
    reduce_kernel<<<dim3(1), dim3(1024), 0, stream>>>(partial, out);
}

// Round 6
// 202.223 us; speedup vs baseline: 1.1954x; 1.0137x over previous
//
#include <hip/hip_runtime.h>

// YOLO loss: BATCH=16384, SNUM=7 -> CELLS=49, BNUM=2, CLSS=20 -> ELE=30.
// Memory-bound streaming reduction: 193 MB in, 4 B out.
//
// v7: persistent never-drain pipeline. v0-v6 all pinned at 2.3-2.8 TB/s
// app BW; the shared structural flaw: every version DRAINS outstanding
// loads to zero at a barrier/block-exit every few KB, so average in-flight
// bytes sit far below the ~3 MB Little's-law requirement for 6.3 TB/s.
// The 6.3 TB/s copy ubench never drains. Fix:
//   - grid = 1280 = 5 blocks/CU x 256 CU, exactly LDS-resident
//     (persistent); each 1-wave block loops ~10 tiles of 64 cells.
//   - wave-private double-buffered LDS (2 x 15360 B): NO barrier needed
//     at all (only this wave reads its LDS) -- pure counted vmcnt.
//   - steady state: issue 15 async global_load_lds for tile t+1 into
//     buf^1, s_waitcnt vmcnt(15) (tile t landed, t+1 stays in flight
//     across compute), compute tile t from buf, flip. vmcnt(0) only on
//     the last tile. ~75 KB continuously in flight per CU.
//   - per-thread acc across tiles -> one wave-reduce -> partial[bid];
//     tiny 1-block reduce kernel writes out (no memset, no atomic).

#define ELE 30
#define TPB 64
#define CPT 64                       // cells per tile (= lanes)
#define FLT_PER_IN (CPT * ELE)       // 1920 floats per input per tile
#define NV4 (FLT_PER_IN / 4)         // 480 float4 per input per tile
#define TILE_FLT (FLT_PER_IN * 2)    // 3840 floats staged per tile (P|T)
#define TOTAL_CELLS (16384 * 49)     // 802816
#define NTILES (TOTAL_CELLS / CPT)   // 12544
#define GRID 1280                    // 5 blocks/CU x 256 CU, LDS-resident

typedef __attribute__((address_space(3))) float       lds_f;
typedef const __attribute__((address_space(1))) float glb_f;

__device__ __forceinline__ void gl_lds16(const float* g, float* l) {
    // 16-byte-per-lane async global->LDS (global_load_lds_dwordx4).
    // LDS dest resolves to wave-uniform base + lane*16 (linear, m104);
    // global src is per-lane.
    __builtin_amdgcn_global_load_lds((glb_f*)g, (lds_f*)l, 16, 0, 0);
}

__device__ __forceinline__ void issue_tile(const float* __restrict__ P,
                                           const float* __restrict__ T,
                                           int tile, float* lbuf, int tid)
{
    const size_t tb = (size_t)tile * FLT_PER_IN;
    const float* Pb = P + tb;
    const float* Tb = T + tb;
    #pragma unroll
    for (int j = 0; j < 15; ++j) {
        const int v = j * 64 + tid;                // float4 idx in [0,960)
        const int vv = (v < NV4) ? v : (v - NV4);
        const float* src = (v < NV4) ? Pb : Tb;    // per-lane select: legal
        gl_lds16(src + (size_t)vv * 4, lbuf + (size_t)v * 4);
    }
}

__device__ __forceinline__ float cell_loss(const float* sbase, int tid)
{
    float cp[ELE], ct[ELE];
    {
        const float2* c2p = reinterpret_cast<const float2*>(sbase + tid * ELE);
        const float2* c2t = reinterpret_cast<const float2*>(sbase + FLT_PER_IN + tid * ELE);
        #pragma unroll
        for (int k = 0; k < ELE / 2; ++k) {
            float2 a = c2p[k];
            cp[2 * k] = a.x; cp[2 * k + 1] = a.y;
            float2 b = c2t[k];
            ct[2 * k] = b.x; ct[2 * k + 1] = b.y;
        }
    }

    const float conf_flag = ct[5];
    const float coord = (conf_flag > 0.0f) ? 1.0f : 0.0f;
    const float noobj = (conf_flag == 0.0f) ? 1.0f : 0.0f;

    const float dc0 = cp[4] - ct[4];
    const float dc1 = cp[9] - ct[9];
    const float noobj_conf = noobj * (dc0 * dc0 + dc1 * dc1);

    float px1[2], py1[2], px2[2], py2[2], pa[2];
    float tx1[2], ty1[2], tx2[2], ty2[2], ta[2];
    #pragma unroll
    for (int b = 0; b < 2; ++b) {
        const int o = b * 5;
        float cx = cp[o + 0], cy = cp[o + 1], w = cp[o + 2], h = cp[o + 3];
        px1[b] = cx - w * 0.5f; py1[b] = cy - h * 0.5f;
        px2[b] = cx + w * 0.5f; py2[b] = cy + h * 0.5f;
        pa[b]  = (px2[b] - px1[b]) * (py2[b] - py1[b]);
        cx = ct[o + 0]; cy = ct[o + 1]; w = ct[o + 2]; h = ct[o + 3];
        tx1[b] = cx - w * 0.5f; ty1[b] = cy - h * 0.5f;
        tx2[b] = cx + w * 0.5f; ty2[b] = cy + h * 0.5f;
        ta[b]  = (tx2[b] - tx1[b]) * (ty2[b] - ty1[b]);
    }

    float iou[2][2];
    #pragma unroll
    for (int p = 0; p < 2; ++p) {
        #pragma unroll
        for (int t = 0; t < 2; ++t) {
            float lx = fmaxf(px1[p], tx1[t]);
            float ly = fmaxf(py1[p], ty1[t]);
            float rx = fminf(px2[p], tx2[t]);
            float ry = fminf(py2[p], ty2[t]);
            float iw = fmaxf(rx - lx, 0.0f);
            float ih = fmaxf(ry - ly, 0.0f);
            float inter = iw * ih;
            iou[p][t] = inter / (pa[p] + ta[t] - inter + 1e-10f);
        }
    }

    // argmax over p per target t; first-max tiebreak -> strict '>' for idx 1
    const int b0 = (iou[1][0] > iou[0][0]) ? 1 : 0;
    const int b1 = (iou[1][1] > iou[0][1]) ? 1 : 0;
    const float resp0 = coord * ((b0 == 0 || b1 == 0) ? 1.0f : 0.0f);
    const float resp1 = coord * ((b0 == 1 || b1 == 1) ? 1.0f : 0.0f);

    const float obj_conf = resp0 * dc0 * dc0 + resp1 * dc1 * dc1;

    float d;
    float center = 0.0f, wh = 0.0f;
    d = cp[0] - ct[0]; center += resp0 * d * d;
    d = cp[1] - ct[1]; center += resp0 * d * d;
    d = cp[5] - ct[5]; center += resp1 * d * d;
    d = cp[6] - ct[6]; center += resp1 * d * d;
    d = cp[2] - ct[2]; wh += resp0 * d * d;
    d = cp[3] - ct[3]; wh += resp0 * d * d;
    d = cp[7] - ct[7]; wh += resp1 * d * d;
    d = cp[8] - ct[8]; wh += resp1 * d * d;

    float cls = 0.0f;
    #pragma unroll
    for (int k = 10; k < 30; ++k) {
        d = cp[k] - ct[k];
        cls += d * d;
    }
    cls *= coord;

    return 5.0f * (center + wh) + obj_conf + 0.5f * noobj_conf + cls;
}

__global__ __launch_bounds__(TPB) void yolo_loss_kernel(
    const float* __restrict__ P, const float* __restrict__ T,
    float* __restrict__ partial)
{
    __shared__ float sbuf[2][TILE_FLT];    // 2 x 15360 B = 30720 B, wave-private

    const int tid = threadIdx.x;
    const int bid = blockIdx.x;

    float acc = 0.0f;
    int cur = 0;

    // prologue: tile 0 of this block into buf0
    issue_tile(P, T, bid, &sbuf[0][0], tid);

    for (int tt = bid; tt < NTILES; tt += GRID) {
        const int nt = tt + GRID;
        if (nt < NTILES) {
            issue_tile(P, T, nt, &sbuf[cur ^ 1][0], tid);
            // tile tt's 15 loads retired; next tile's 15 stay in flight
            asm volatile("s_waitcnt vmcnt(15)" ::: "memory");
        } else {
            asm volatile("s_waitcnt vmcnt(0)" ::: "memory");
        }
        __builtin_amdgcn_sched_barrier(0);   // keep ds_reads below the wait
        acc += cell_loss(&sbuf[cur][0], tid);
        cur ^= 1;
    }

    // ---- wave reduction -> one partial store per block ----
    #pragma unroll
    for (int off = 32; off > 0; off >>= 1)
        acc += __shfl_down(acc, off, 64);

    if (tid == 0)
        partial[bid] = acc;
}

__global__ __launch_bounds__(1024) void reduce_kernel(
    const float* __restrict__ partial, float* __restrict__ out)
{
    __shared__ float sw[16];
    const int tid = threadIdx.x;

    float s = 0.0f;
    for (int i = tid; i < GRID; i += 1024)
        s += partial[i];

    #pragma unroll
    for (int off = 32; off > 0; off >>= 1)
        s += __shfl_down(s, off, 64);

    const int wid = tid >> 6;
    const int lane = tid & 63;
    if (lane == 0) sw[wid] = s;
    __syncthreads();
    if (tid == 0) {
        float t = 0.0f;
        #pragma unroll
        for (int i = 0; i < 16; ++i) t += sw[i];
        *out = t;           // unconditional write: no memset needed
    }
}

extern "C" void kernel_launch(void* const* d_in, const int* in_sizes, int n_in,
                              void* d_out, int out_size, void* d_ws, size_t ws_size,
                              hipStream_t stream) {
    const float* P = (const float*)d_in[0];
    const float* T = (const float*)d_in[1];
    float* out = (float*)d_out;
    float* partial = (float*)d_ws;        // needs GRID*4 = 5120 B of workspace

    yolo_loss_kernel<<<dim3(GRID), dim3(TPB), 0, stream>>>(P, T, partial);
    reduce_kernel<<<dim3(1), dim3(1024), 0, stream>>>(partial, out);
}